// Round 5
// baseline (394.226 us; speedup 1.0000x reference)
//
#include <hip/hip_runtime.h>
#include <hip/hip_bf16.h>
#include <math.h>

typedef __hip_bfloat16 bf16;
typedef __bf16 bf16x8 __attribute__((ext_vector_type(8)));
typedef float f32x4 __attribute__((ext_vector_type(4)));

static __device__ __forceinline__ float b2f(bf16 v) { return __bfloat162float(v); }
static __device__ __forceinline__ bf16 f2b(float v) { return __float2bfloat16(v); }

// async global->LDS, 16B per lane; LDS dest = wave-uniform base + lane*16
#define GLOAD16(g, l) __builtin_amdgcn_global_load_lds( \
    (const __attribute__((address_space(1))) void*)(g), \
    (__attribute__((address_space(3))) void*)(l), 16, 0, 0)

// ---------------------------------------------------------------------------
// Weights-stationary barrier-free GEMM template:
//   D[m][n] = sum_k A[mt*32+i][kOff+k] * Bt[n][kOff+k]  (+ bias)
// A-tile (32 x KSL) staged to LDS ONCE (XOR-swizzled source so ds_read_b128
// fragments are conflict-free); B streamed global->VGPR; NO barriers in the
// K-loop -- waves are fully independent, compiler pipelines loads vs MFMA.
// Block 256 thr = 4 waves; wave w owns n-sub [n0+w*64, +64); acc[2][4].
// Grid 1-D: id&7 = batch (XCD pin); slot: mt fastest, then nc, then k-split.
// ---------------------------------------------------------------------------
template <typename TOUT, int KSL>
__global__ __launch_bounds__(256) void gemm_ws(
    const bf16* __restrict__ A, size_t sA, int lda,
    const bf16* __restrict__ Bt, size_t sB, int ldb,
    const float* __restrict__ bias, size_t sBias, int hasBias,
    TOUT* __restrict__ D, size_t sD, size_t sDs,
    int N, int NMT, int NNC)
{
    constexpr int KSTEPS = KSL / 32;
    const int id = blockIdx.x;
    const int bz = id & 7;                  // batch -> XCD pin
    int slot = id >> 3;
    const int mt = slot % NMT; slot /= NMT;
    const int nc = slot % NNC;
    const int ks = slot / NNC;              // k-split index
    const int n0 = nc * 256;

    A  += (size_t)bz * sA + (size_t)(mt * 32) * lda + (size_t)ks * KSL;
    Bt += (size_t)bz * sB + (size_t)ks * KSL;
    D  += (size_t)bz * sD + (size_t)ks * sDs;
    if (hasBias) bias += (size_t)bz * sBias + mt * 32;

    const int t = threadIdx.x, wv = t >> 6, lane = t & 63;
    const int lr = lane & 15, quad = lane >> 4;
    const int xr7 = lr & 7;

    __shared__ bf16 lA[32 * KSL];

    // ---- stage A once: rows [wv*8, wv*8+8), source col-block XOR (r&7) ----
    if constexpr (KSL == 512) {
#pragma unroll
        for (int rr = 0; rr < 8; ++rr) {
            const int r = wv * 8 + rr;
            GLOAD16(A + (size_t)r * lda + ((lane ^ (r & 7)) << 3), &lA[r * 512]);
        }
    } else {  // KSL == 256: one instruction stages two rows (lanes 32-63 -> r+1)
#pragma unroll
        for (int rr = 0; rr < 4; ++rr) {
            const int rb = wv * 8 + rr * 2;
            const int rl = rb + (lane >> 5);
            GLOAD16(A + (size_t)rl * lda + (((lane & 31) ^ (rl & 7)) << 3),
                    &lA[rb * 256]);
        }
    }
    __syncthreads();   // the ONLY barrier

    f32x4 acc[2][4];
#pragma unroll
    for (int i = 0; i < 2; ++i)
#pragma unroll
        for (int j = 0; j < 4; ++j) acc[i][j] = (f32x4){0.f, 0.f, 0.f, 0.f};

    const bf16* bp[4];
#pragma unroll
    for (int j = 0; j < 4; ++j)
        bp[j] = Bt + (size_t)(n0 + wv * 64 + j * 16 + lr) * ldb + quad * 8;

#pragma unroll 2
    for (int k2 = 0; k2 < KSTEPS; ++k2) {
        const int ao = ((((k2 << 2) | quad) ^ xr7) << 3);
        bf16x8 bfr[4];
#pragma unroll
        for (int j = 0; j < 4; ++j)
            bfr[j] = *(const bf16x8*)(bp[j] + k2 * 32);
        bf16x8 af0 = *(const bf16x8*)&lA[lr * KSL + ao];
        bf16x8 af1 = *(const bf16x8*)&lA[(16 + lr) * KSL + ao];
#pragma unroll
        for (int j = 0; j < 4; ++j) {
            acc[0][j] = __builtin_amdgcn_mfma_f32_16x16x32_bf16(af0, bfr[j], acc[0][j], 0, 0, 0);
            acc[1][j] = __builtin_amdgcn_mfma_f32_16x16x32_bf16(af1, bfr[j], acc[1][j], 0, 0, 0);
        }
    }

#pragma unroll
    for (int i = 0; i < 2; ++i) {
#pragma unroll
        for (int r = 0; r < 4; ++r) {
            const int ml = i * 16 + quad * 4 + r;      // 0..31 in tile
            const int mrow = mt * 32 + ml;
            const float bvv = hasBias ? bias[ml] : 0.f;
#pragma unroll
            for (int j = 0; j < 4; ++j) {
                const int nn = n0 + wv * 64 + j * 16 + lr;
                const float v = acc[i][j][r] + bvv;
                if constexpr (__is_same(TOUT, float)) D[(size_t)mrow * N + nn] = v;
                else                                  D[(size_t)mrow * N + nn] = f2b(v);
            }
        }
    }
}

// ---------------------------------------------------------------------------
// QKV: same weights-stationary barrier-free design, specialized.
// A = wqkv_g[b][768][512] (scale folded), B = xT[b][4096][512].
// Block 512 thr = 8 waves; m-tile 64 (LDS 64KB); wave owns 64n of a 512n
// chunk; acc[4][4]. Grid 12 mt x 8 nc x 8 b = 768, id&7 = batch.
// ---------------------------------------------------------------------------
__global__ __launch_bounds__(512, 4) void gemm_qkv3(
    const bf16* __restrict__ Aall, const bf16* __restrict__ xT,
    const float* __restrict__ bias,
    bf16* __restrict__ qb, bf16* __restrict__ kb, bf16* __restrict__ vT)
{
    const int id = blockIdx.x;
    const int b = id & 7;
    const int slot = id >> 3;          // 0..95
    const int mt = slot % 12;          // m-tile fastest (shares B panel)
    const int n0 = (slot / 12) * 512;

    const bf16* A  = Aall + (size_t)b * 393216 + (size_t)(mt * 64) * 512;
    const bf16* Bt = xT + (size_t)b * 2097152;
    bias += b * 768 + mt * 64;

    const int t = threadIdx.x, w = t >> 6, lane = t & 63;
    const int lr = lane & 15, quad = lane >> 4;
    const int xr7 = lr & 7;

    __shared__ bf16 lA[64 * 512];

#pragma unroll
    for (int rr = 0; rr < 8; ++rr) {
        const int r = w * 8 + rr;
        GLOAD16(A + (size_t)r * 512 + ((lane ^ (r & 7)) << 3), &lA[r * 512]);
    }
    __syncthreads();   // the ONLY barrier

    f32x4 acc[4][4];
#pragma unroll
    for (int i = 0; i < 4; ++i)
#pragma unroll
        for (int j = 0; j < 4; ++j) acc[i][j] = (f32x4){0.f, 0.f, 0.f, 0.f};

    const bf16* bp0 = Bt + (size_t)(n0 + w * 64 + lr) * 512 + quad * 8;

    for (int k2 = 0; k2 < 16; ++k2) {
        const int ao = ((((k2 << 2) | quad) ^ xr7) << 3);
        bf16x8 bfr[4];
#pragma unroll
        for (int j = 0; j < 4; ++j)
            bfr[j] = *(const bf16x8*)(bp0 + (size_t)j * 8192 + k2 * 32);
        bf16x8 af[4];
#pragma unroll
        for (int i = 0; i < 4; ++i)
            af[i] = *(const bf16x8*)&lA[(i * 16 + lr) * 512 + ao];
#pragma unroll
        for (int i = 0; i < 4; ++i)
#pragma unroll
            for (int j = 0; j < 4; ++j)
                acc[i][j] = __builtin_amdgcn_mfma_f32_16x16x32_bf16(af[i], bfr[j], acc[i][j], 0, 0, 0);
    }

    // mt 0-3 -> q, 4-7 -> k, 8-11 -> v (block-uniform branch)
#pragma unroll
    for (int i = 0; i < 4; ++i) {
#pragma unroll
        for (int r = 0; r < 4; ++r) {
            const int ml = i * 16 + quad * 4 + r;     // 0..63
            const int mmg = mt * 64 + ml;             // 0..767
            const int mloc = mmg & 255;
            const float bvv = bias[ml];
#pragma unroll
            for (int j = 0; j < 4; ++j) {
                const int nn = n0 + w * 64 + j * 16 + lr;
                const float v = acc[i][j][r] + bvv;
                if (mt < 4)       qb[(size_t)b * 1048576 + (size_t)mloc * 4096 + nn] = f2b(v);
                else if (mt < 8)  kb[(size_t)b * 1048576 + (size_t)mloc * 4096 + nn] = f2b(v);
                else              vT[(size_t)b * 1048576 + (size_t)nn * 256 + mloc] = f2b(v);
            }
        }
    }
}

// ---------------------------------------------------------------------------
// x prep: x[b][512][4096] f32 -> xT[b][4096][512] bf16 (transpose+cast),
// fused per-channel partial sums xsump[8][b*512+c].
// ---------------------------------------------------------------------------
__global__ __launch_bounds__(256) void k_prep(const float* __restrict__ x,
                                              bf16* __restrict__ xT,
                                              float* __restrict__ xsump)
{
    const int b = blockIdx.z;
    const int c0 = blockIdx.y * 64;
    const int n0 = blockIdx.x * 512;
    const int t = threadIdx.x;
    const int cr = t >> 2;        // 0..63
    const int sub = t & 3;        // 0..3
    __shared__ bf16 tile[64][72];

    const float* xrow = x + ((size_t)b * 512 + c0 + cr) * 4096 + n0 + sub * 16;
    float s = 0.f;

    for (int st = 0; st < 8; ++st) {
        __syncthreads();
        float4 f[4];
#pragma unroll
        for (int q = 0; q < 4; ++q) f[q] = *(const float4*)(xrow + st * 64 + q * 4);
#pragma unroll
        for (int q = 0; q < 4; ++q) {
            s += f[q].x + f[q].y + f[q].z + f[q].w;
            union { bf16 h[4]; uint2 u; } p;
            p.h[0] = f2b(f[q].x); p.h[1] = f2b(f[q].y);
            p.h[2] = f2b(f[q].z); p.h[3] = f2b(f[q].w);
            *(uint2*)&tile[cr][sub * 16 + q * 4] = p.u;
        }
        __syncthreads();
        union { bf16 h[8]; uint4 u; } o0, o1;
#pragma unroll
        for (int i = 0; i < 8; ++i) o0.h[i] = tile[sub * 16 + i][cr];
#pragma unroll
        for (int i = 0; i < 8; ++i) o1.h[i] = tile[sub * 16 + 8 + i][cr];
        bf16* orow = xT + ((size_t)b * 4096 + n0 + st * 64 + cr) * 512 + c0 + sub * 16;
        *(uint4*)(orow)     = o0.u;
        *(uint4*)(orow + 8) = o1.u;
    }
    s += __shfl_down(s, 2);
    s += __shfl_down(s, 1);
    if (sub == 0) xsump[(size_t)blockIdx.x * 4096 + b * 512 + c0 + cr] = s;
}

// ---------------------------------------------------------------------------
// Small kernels
// ---------------------------------------------------------------------------

__global__ void k_smallgemm(const float* __restrict__ in, const float* __restrict__ W,
                            const float* __restrict__ bias, float* __restrict__ out,
                            int Mrows, int O, int Kd, int act, int inAct)
{
    const int gw = (blockIdx.x * 256 + threadIdx.x) >> 6;
    const int lane = threadIdx.x & 63;
    if (gw >= Mrows * O) return;
    const int m = gw / O, o = gw - m * O;
    float s = 0.f;
    for (int k = lane; k < Kd; k += 64) {
        float iv = in[m * Kd + k];
        if (inAct) iv = iv / (1.f + expf(-iv));
        s += iv * W[(size_t)o * Kd + k];
    }
    for (int off = 32; off; off >>= 1) s += __shfl_down(s, off);
    if (lane == 0) {
        s += bias[o];
        if (act) s = s / (1.f + expf(-s));
        out[m * O + o] = s;
    }
}

__global__ void k_mlp1(const float* __restrict__ ss, const float* __restrict__ xsump,
                       const float* __restrict__ tp, const float* __restrict__ w_m1,
                       const float* __restrict__ b_m1, float* __restrict__ hidden)
{
    const int gw = (blockIdx.x * 256 + threadIdx.x) >> 6;
    const int lane = threadIdx.x & 63;
    if (gw >= 8 * 1024) return;
    const int m = gw >> 10, o = gw & 1023;
    float s = 0.f;
    for (int k = lane; k < 1024; k += 64) {
        float pv;
        if (k < 512) {
            float xs = 0.f;
#pragma unroll
            for (int p = 0; p < 8; ++p) xs += xsump[p * 4096 + m * 512 + k];
            pv = (1.f + ss[m * 1024 + k]) * (xs * (1.f / 4096.f))
                 + ss[m * 1024 + 512 + k];
        } else {
            pv = tp[m * 512 + k - 512];
        }
        s += pv * w_m1[(size_t)o * 1024 + k];
    }
    for (int off = 32; off; off >>= 1) s += __shfl_down(s, off);
    if (lane == 0) {
        s += b_m1[o];
        hidden[m * 1024 + o] = s / (1.f + expf(-s));
    }
}

__global__ void k_topk(const float* __restrict__ prompt, int* __restrict__ idx)
{
    __shared__ float v[512];
    __shared__ int sel[512];
    const int b = blockIdx.x, c = threadIdx.x;
    v[c] = prompt[b * 512 + c];
    __syncthreads();
    const float mv = v[c];
    int rank = 0;
    for (int j = 0; j < 512; ++j) {
        float o = v[j];
        rank += (o > mv) || (o == mv && j < c);
    }
    sel[c] = (rank < 256) ? 1 : 0;
    __syncthreads();
    if (rank < 256) {
        int pos = 0;
        for (int j = 0; j < c; ++j) pos += sel[j];
        idx[b * 256 + pos] = c;
    }
}

__global__ void k_gather(const int* __restrict__ idx, const float* __restrict__ ss,
                         const float* __restrict__ wq, const float* __restrict__ wk,
                         const float* __restrict__ wv, const float* __restrict__ wo,
                         bf16* __restrict__ wqkv_g, bf16* __restrict__ wo_g)
{
    const int b = blockIdx.z;
    const int* id = idx + b * 256;
    const int tid = blockIdx.x * 256 + threadIdx.x;  // < 393216
    {
        const int mat = tid >> 17, r = tid & 131071;
        const int j = r >> 9, c = r & 511;
        const int ch = id[j];
        const float* W = mat == 0 ? wq : (mat == 1 ? wk : wv);
        wqkv_g[(size_t)b * 393216 + tid] = f2b(W[ch * 512 + c] * (1.f + ss[b * 1024 + c]));
    }
    if (tid < 131072) {
        const int o = tid >> 8, j = tid & 255;
        wo_g[(size_t)b * 131072 + tid] = f2b(wo[o * 512 + id[j]]);
    }
}

__global__ void k_biasadj(const int* __restrict__ idx, const float* __restrict__ ss,
                          const float* __restrict__ wq, const float* __restrict__ bq,
                          const float* __restrict__ wk, const float* __restrict__ bk,
                          const float* __restrict__ wv, const float* __restrict__ bv,
                          float* __restrict__ bqkv)
{
    const int gw = (blockIdx.x * 256 + threadIdx.x) >> 6;
    const int lane = threadIdx.x & 63;
    if (gw >= 8 * 768) return;
    const int b = gw / 768, j3 = gw - b * 768;
    const int mat = j3 >> 8, j = j3 & 255;
    const int ch = idx[b * 256 + j];
    const float* W  = mat == 0 ? wq : (mat == 1 ? wk : wv);
    const float* Bb = mat == 0 ? bq : (mat == 1 ? bk : bv);
    const float* shift = ss + b * 1024 + 512;
    float s = 0.f;
    for (int c = lane; c < 512; c += 64)
        s += W[(size_t)ch * 512 + c] * shift[c];
    for (int off = 32; off; off >>= 1) s += __shfl_down(s, off);
    if (lane == 0) bqkv[b * 768 + j3] = Bb[ch] + s;
}

// reduce 8 fp32 split-K partials, softmax row (scale 1/16 = 256^-0.5), write P^T
__global__ void k_softmax_red(const float* __restrict__ part, bf16* __restrict__ Pt)
{
    const int row = blockIdx.x;          // b*256 + j
    const int b = row >> 8, j = row & 255;
    const int t = threadIdx.x;
    const int lane = t & 63, wv = t >> 6;
    __shared__ float redm[4], reds[4];
    float v = 0.f;
#pragma unroll
    for (int s = 0; s < 8; ++s)
        v += part[((size_t)(s * 8 + b) * 256 + j) * 256 + t];
    v *= 0.0625f;
    float m = v;
    for (int off = 32; off; off >>= 1) m = fmaxf(m, __shfl_down(m, off));
    if (lane == 0) redm[wv] = m;
    __syncthreads();
    m = fmaxf(fmaxf(redm[0], redm[1]), fmaxf(redm[2], redm[3]));
    const float e = __expf(v - m);
    float s = e;
    for (int off = 32; off; off >>= 1) s += __shfl_down(s, off);
    if (lane == 0) reds[wv] = s;
    __syncthreads();
    s = reds[0] + reds[1] + reds[2] + reds[3];
    Pt[(size_t)b * 65536 + (size_t)t * 256 + j] = f2b(e / s);  // P^T
}

// ---------------------------------------------------------------------------

extern "C" void kernel_launch(void* const* d_in, const int* in_sizes, int n_in,
                              void* d_out, int out_size, void* d_ws, size_t ws_size,
                              hipStream_t stream)
{
    const float* x        = (const float*)d_in[0];
    const float* temb     = (const float*)d_in[1];
    const float* w_affine = (const float*)d_in[2];
    const float* b_affine = (const float*)d_in[3];
    const float* w_tp     = (const float*)d_in[4];
    const float* b_tp     = (const float*)d_in[5];
    const float* w_m1     = (const float*)d_in[6];
    const float* b_m1     = (const float*)d_in[7];
    const float* w_m2     = (const float*)d_in[8];
    const float* b_m2     = (const float*)d_in[9];
    const float* wq       = (const float*)d_in[10];
    const float* bq       = (const float*)d_in[11];
    const float* wk       = (const float*)d_in[12];
    const float* bk       = (const float*)d_in[13];
    const float* wv       = (const float*)d_in[14];
    const float* bv       = (const float*)d_in[15];
    const float* wo       = (const float*)d_in[16];
    const float* bo       = (const float*)d_in[17];
    float* out = (float*)d_out;

    char* ws = (char*)d_ws;
    size_t off = 0;
    auto alloc = [&](size_t bytes) -> char* {
        char* p = ws + off;
        off += (bytes + 255) & ~(size_t)255;
        return p;
    };

    float* ssb      = (float*)alloc(8192 * 4);
    float* tp       = (float*)alloc(4096 * 4);
    float* xsump    = (float*)alloc((size_t)8 * 4096 * 4);
    float* hidden   = (float*)alloc(8192 * 4);
    float* prompt   = (float*)alloc(4096 * 4);
    int*   idx      = (int*)alloc(2048 * 4);
    bf16*  xT     = (bf16*)alloc((size_t)8 * 4096 * 512 * 2);
    float* part   = (float*)alloc((size_t)8 * 8 * 256 * 256 * 4);  // split-K partials
    bf16*  wqkv_g = (bf16*)alloc((size_t)8 * 768 * 512 * 2);
    float* bqkv_g = (float*)alloc(8 * 768 * 4);
    bf16*  wo_g   = (bf16*)alloc((size_t)8 * 512 * 256 * 2);
    bf16*  qb     = (bf16*)alloc((size_t)8 * 256 * 4096 * 2);
    bf16*  kb     = (bf16*)alloc((size_t)8 * 256 * 4096 * 2);
    bf16*  vT     = (bf16*)alloc((size_t)8 * 4096 * 256 * 2);
    bf16*  Pt     = (bf16*)alloc((size_t)8 * 256 * 256 * 2);
    bf16*  W2     = (bf16*)alloc((size_t)8 * 512 * 256 * 2);
    (void)ws_size; (void)n_in; (void)in_sizes; (void)out_size;

    // x transpose->bf16 + channel sums
    k_prep<<<dim3(8, 8, 8), 256, 0, stream>>>(x, xT, xsump);
    // silu fused into the input reads of the two temb GEMMs
    k_smallgemm<<<2048, 256, 0, stream>>>(temb, w_affine, b_affine, ssb, 8, 1024, 512, 0, 1);
    k_smallgemm<<<1024, 256, 0, stream>>>(temb, w_tp, b_tp, tp, 8, 512, 512, 0, 1);
    k_mlp1<<<2048, 256, 0, stream>>>(ssb, xsump, tp, w_m1, b_m1, hidden);
    k_smallgemm<<<1024, 256, 0, stream>>>(hidden, w_m2, b_m2, prompt, 8, 512, 1024, 0, 0);
    k_topk<<<8, 512, 0, stream>>>(prompt, idx);
    k_gather<<<dim3(1536, 1, 8), 256, 0, stream>>>(idx, ssb, wq, wk, wv, wo, wqkv_g, wo_g);
    k_biasadj<<<1536, 256, 0, stream>>>(idx, ssb, wq, bq, wk, bk, wv, bv, bqkv_g);

    // QKV: barrier-free weights-stationary (12 mt x 8 nc x 8 b = 768 blocks)
    gemm_qkv3<<<768, 512, 0, stream>>>(wqkv_g, xT, bqkv_g, qb, kb, vT);

    // S split-K: A=q m-tiles stationary, B=k streamed. 8 mt x 1 nc x 8 splits x 8 b
    gemm_ws<float, 512><<<512, 256, 0, stream>>>(
        qb, 1048576, 4096, kb, 1048576, 4096,
        nullptr, 0, 0,
        part, 65536, 524288, 256, 8, 1);

    // softmax + split reduction -> P^T
    k_softmax_red<<<2048, 256, 0, stream>>>(part, Pt);

    // W2 = wo_g @ P  (512x256, K=256): 16 mt x 1 nc x 8 b = 128 blocks
    gemm_ws<bf16, 256><<<128, 256, 0, stream>>>(
        wo_g, 131072, 256, Pt, 65536, 256,
        nullptr, 0, 0,
        W2, 131072, 0, 256, 16, 1);

    // out = W2 @ v + bo  (512x4096, K=256): 16 mt x 16 nc x 8 b = 2048 blocks
    gemm_ws<float, 256><<<2048, 256, 0, stream>>>(
        W2, 131072, 256, vT, 1048576, 256,
        bo, 0, 1,
        out, 2097152, 0, 4096, 16, 16);
}

// Round 7
// 367.271 us; speedup vs baseline: 1.0734x; 1.0734x over previous
//
#include <hip/hip_runtime.h>
#include <hip/hip_bf16.h>
#include <math.h>

typedef __hip_bfloat16 bf16;
typedef __bf16 bf16x8 __attribute__((ext_vector_type(8)));
typedef float f32x4 __attribute__((ext_vector_type(4)));

static __device__ __forceinline__ float b2f(bf16 v) { return __bfloat162float(v); }
static __device__ __forceinline__ bf16 f2b(float v) { return __float2bfloat16(v); }

// async global->LDS, 16B per lane; LDS dest = wave-uniform base + lane*16
#define GLOAD16(g, l) __builtin_amdgcn_global_load_lds( \
    (const __attribute__((address_space(1))) void*)(g), \
    (__attribute__((address_space(3))) void*)(l), 16, 0, 0)

#define WAITVM(N) asm volatile("s_waitcnt vmcnt(" #N ")" ::: "memory")

// ---------------------------------------------------------------------------
// Generic MFMA GEMM (round-4-verified body, generalized):
//   D[m][n] = sum_{k<kLen} A[m][ks*kLen+k] * Bt[n][ks*kLen+k]  (+ bias[m])
// Tile 128x64, BK=32, 3-deep LDS rotation + counted vmcnt(3) + s_barrier.
// LDS 16B-block XOR swizzle (verified conflict-free round 3).
// Grid 1-D = 8 * NXB * NYB * KS; id&7 = batch (XCD pin); bx fastest.
// ---------------------------------------------------------------------------
#define TM 128
#define TN 64
#define TK 32

template <typename TOUT>
__global__ __launch_bounds__(256) void gemm_bt2(
    const bf16* __restrict__ A, size_t sA, int lda,
    const bf16* __restrict__ Bt, size_t sB, int ldb,
    const float* __restrict__ bias, size_t sBias, int hasBias,
    TOUT* __restrict__ D, size_t sD, size_t sDk,
    int M, int N, int kLen, int transStore, int NXB, int NYB)
{
    const int id = blockIdx.x;
    const int bz = id & 7;          // batch -> XCD pin
    int slot = id >> 3;
    const int bx = slot % NXB; slot /= NXB;
    const int by = slot % NYB;
    const int ks = slot / NYB;      // k-split

    A  += (size_t)bz * sA + (size_t)ks * kLen;
    Bt += (size_t)bz * sB + (size_t)ks * kLen;
    D  += (size_t)bz * sD + (size_t)ks * sDk;
    if (hasBias) bias += (size_t)bz * sBias;

    const int m0 = by * TM, n0 = bx * TN;
    const int t = threadIdx.x, wv = t >> 6, lane = t & 63;
    const int lr = lane & 15, quad = lane >> 4;
    const int qx8 = (quad ^ ((lr >> 1) & 3)) * 8;      // swizzled read offset

    __shared__ bf16 lA[3][TM * TK];
    __shared__ bf16 lB[3][TN * TK];

    f32x4 acc[2][4];
#pragma unroll
    for (int i = 0; i < 2; ++i)
#pragma unroll
        for (int j = 0; j < 4; ++j) acc[i][j] = (f32x4){0.f, 0.f, 0.f, 0.f};

    const int srow = lane >> 2;
    const int scol = ((lane & 3) ^ ((lane >> 3) & 3)) * 8;
    const bf16* as0 = A  + (size_t)(m0 + wv * 16 + srow) * lda + scol;
    const bf16* bs0 = Bt + (size_t)(n0 + wv * 16 + srow) * ldb + scol;

    // prologue: stage k-tiles 0 and 1 (kLen >= 64 always)
    GLOAD16(as0, &lA[0][wv * 512]);
    GLOAD16(as0 + (size_t)64 * lda, &lA[0][wv * 512 + 2048]);
    GLOAD16(bs0, &lB[0][wv * 512]);
    GLOAD16(as0 + TK, &lA[1][wv * 512]);
    GLOAD16(as0 + (size_t)64 * lda + TK, &lA[1][wv * 512 + 2048]);
    GLOAD16(bs0 + TK, &lB[1][wv * 512]);
    WAITVM(3);
    __builtin_amdgcn_s_barrier();

    int cur = 0;
    for (int k0 = 0; k0 < kLen; k0 += TK) {
        int kn = k0 + 2 * TK; if (kn >= kLen) kn -= kLen;  // tail: dummy reload (dead buf)
        int nx2 = cur + 2; if (nx2 >= 3) nx2 -= 3;
        GLOAD16(as0 + kn, &lA[nx2][wv * 512]);
        GLOAD16(as0 + (size_t)64 * lda + kn, &lA[nx2][wv * 512 + 2048]);
        GLOAD16(bs0 + kn, &lB[nx2][wv * 512]);

        const bf16* bA = lA[cur];
        const bf16* bB = lB[cur];
        bf16x8 af0 = *(const bf16x8*)(bA + (wv * 32 + lr) * 32 + qx8);
        bf16x8 af1 = *(const bf16x8*)(bA + (wv * 32 + 16 + lr) * 32 + qx8);
#pragma unroll
        for (int j = 0; j < 4; ++j) {
            bf16x8 bfj = *(const bf16x8*)(bB + (j * 16 + lr) * 32 + qx8);
            acc[0][j] = __builtin_amdgcn_mfma_f32_16x16x32_bf16(af0, bfj, acc[0][j], 0, 0, 0);
            acc[1][j] = __builtin_amdgcn_mfma_f32_16x16x32_bf16(af1, bfj, acc[1][j], 0, 0, 0);
        }
        WAITVM(3);
        __builtin_amdgcn_s_barrier();
        cur = (cur + 1 == 3) ? 0 : cur + 1;
    }

#pragma unroll
    for (int i = 0; i < 2; ++i) {
        const int mb = m0 + wv * 32 + i * 16 + quad * 4;
#pragma unroll
        for (int r = 0; r < 4; ++r) {
            const int mm = mb + r;
            const float bvv = hasBias ? bias[mm] : 0.f;
#pragma unroll
            for (int j = 0; j < 4; ++j) {
                const int nn = n0 + j * 16 + lr;
                const float v = acc[i][j][r] + bvv;
                const size_t o = transStore ? ((size_t)nn * M + mm)
                                            : ((size_t)mm * N + nn);
                if constexpr (__is_same(TOUT, float)) D[o] = v;
                else                                  D[o] = f2b(v);
            }
        }
    }
}

// ---------------------------------------------------------------------------
// x prep: x[b][512][4096] f32 -> xb bf16 natural [b][512][4096]
//                             -> xT bf16 transposed [b][4096][512]
//                             + per-channel partial sums xsump[8][b*512+c].
// Grid (8 n-chunks of 512, 8 c-chunks of 64, 8 batches), 256 thr.
// ---------------------------------------------------------------------------
__global__ __launch_bounds__(256) void k_prep2(const float* __restrict__ x,
                                               bf16* __restrict__ xb,
                                               bf16* __restrict__ xT,
                                               float* __restrict__ xsump)
{
    const int b = blockIdx.z;
    const int c0 = blockIdx.y * 64;
    const int n0 = blockIdx.x * 512;
    const int t = threadIdx.x;
    const int cr = t >> 2;        // 0..63
    const int sub = t & 3;        // 0..3
    __shared__ bf16 tile[64][72];

    const size_t rowoff = ((size_t)b * 512 + c0 + cr) * 4096 + n0 + sub * 16;
    const float* xrow = x + rowoff;
    bf16* xbrow = xb + rowoff;
    float s = 0.f;

    for (int st = 0; st < 8; ++st) {
        __syncthreads();
        float4 f[4];
#pragma unroll
        for (int q = 0; q < 4; ++q) f[q] = *(const float4*)(xrow + st * 64 + q * 4);
        union { bf16 h[16]; uint4 u[2]; } pk;
#pragma unroll
        for (int q = 0; q < 4; ++q) {
            s += f[q].x + f[q].y + f[q].z + f[q].w;
            pk.h[q * 4 + 0] = f2b(f[q].x); pk.h[q * 4 + 1] = f2b(f[q].y);
            pk.h[q * 4 + 2] = f2b(f[q].z); pk.h[q * 4 + 3] = f2b(f[q].w);
            *(uint2*)&tile[cr][sub * 16 + q * 4] = *(uint2*)&pk.h[q * 4];
        }
        *(uint4*)(xbrow + st * 64)     = pk.u[0];
        *(uint4*)(xbrow + st * 64 + 8) = pk.u[1];
        __syncthreads();
        union { bf16 h[8]; uint4 u; } o0, o1;
#pragma unroll
        for (int i = 0; i < 8; ++i) o0.h[i] = tile[sub * 16 + i][cr];
#pragma unroll
        for (int i = 0; i < 8; ++i) o1.h[i] = tile[sub * 16 + 8 + i][cr];
        bf16* orow = xT + ((size_t)b * 4096 + n0 + st * 64 + cr) * 512 + c0 + sub * 16;
        *(uint4*)(orow)     = o0.u;
        *(uint4*)(orow + 8) = o1.u;
    }
    s += __shfl_down(s, 2);
    s += __shfl_down(s, 1);
    if (sub == 0) xsump[(size_t)blockIdx.x * 4096 + b * 512 + c0 + cr] = s;
}

// ---------------------------------------------------------------------------
// Small kernels
// ---------------------------------------------------------------------------

__global__ void k_smallgemm(const float* __restrict__ in, const float* __restrict__ W,
                            const float* __restrict__ bias, float* __restrict__ out,
                            int Mrows, int O, int Kd, int act, int inAct)
{
    const int gw = (blockIdx.x * 256 + threadIdx.x) >> 6;
    const int lane = threadIdx.x & 63;
    if (gw >= Mrows * O) return;
    const int m = gw / O, o = gw - m * O;
    float s = 0.f;
    for (int k = lane; k < Kd; k += 64) {
        float iv = in[m * Kd + k];
        if (inAct) iv = iv / (1.f + expf(-iv));
        s += iv * W[(size_t)o * Kd + k];
    }
    for (int off = 32; off; off >>= 1) s += __shfl_down(s, off);
    if (lane == 0) {
        s += bias[o];
        if (act) s = s / (1.f + expf(-s));
        out[m * O + o] = s;
    }
}

__global__ void k_mlp1(const float* __restrict__ ss, const float* __restrict__ xsump,
                       const float* __restrict__ tp, const float* __restrict__ w_m1,
                       const float* __restrict__ b_m1, float* __restrict__ hidden)
{
    const int gw = (blockIdx.x * 256 + threadIdx.x) >> 6;
    const int lane = threadIdx.x & 63;
    if (gw >= 8 * 1024) return;
    const int m = gw >> 10, o = gw & 1023;
    float s = 0.f;
    for (int k = lane; k < 1024; k += 64) {
        float pv;
        if (k < 512) {
            float xs = 0.f;
#pragma unroll
            for (int p = 0; p < 8; ++p) xs += xsump[p * 4096 + m * 512 + k];
            pv = (1.f + ss[m * 1024 + k]) * (xs * (1.f / 4096.f))
                 + ss[m * 1024 + 512 + k];
        } else {
            pv = tp[m * 512 + k - 512];
        }
        s += pv * w_m1[(size_t)o * 1024 + k];
    }
    for (int off = 32; off; off >>= 1) s += __shfl_down(s, off);
    if (lane == 0) {
        s += b_m1[o];
        hidden[m * 1024 + o] = s / (1.f + expf(-s));
    }
}

__global__ void k_topk(const float* __restrict__ prompt, int* __restrict__ idx)
{
    __shared__ float v[512];
    __shared__ int sel[512];
    const int b = blockIdx.x, c = threadIdx.x;
    v[c] = prompt[b * 512 + c];
    __syncthreads();
    const float mv = v[c];
    int rank = 0;
    for (int j = 0; j < 512; ++j) {
        float o = v[j];
        rank += (o > mv) || (o == mv && j < c);
    }
    sel[c] = (rank < 256) ? 1 : 0;
    __syncthreads();
    if (rank < 256) {
        int pos = 0;
        for (int j = 0; j < c; ++j) pos += sel[j];
        idx[b * 256 + pos] = c;
    }
}

// per-channel modulation vectors: smod=1+scale, shm=shift, xst=rowsum(x),
// rsh = rowsum(h) = smod*xst + 4096*shm
__global__ void k_mod(const float* __restrict__ ssb, const float* __restrict__ xsump,
                      float* __restrict__ smod, float* __restrict__ shm,
                      float* __restrict__ xst, float* __restrict__ rsh)
{
    const int g = blockIdx.x * 256 + threadIdx.x;
    if (g >= 4096) return;
    const int b = g >> 9, c = g & 511;
    float xs = 0.f;
#pragma unroll
    for (int p = 0; p < 8; ++p) xs += xsump[p * 4096 + b * 512 + c];
    const float sm = 1.f + ssb[b * 1024 + c];
    const float sh = ssb[b * 1024 + 512 + c];
    smod[g] = sm; shm[g] = sh; xst[g] = xs;
    rsh[g] = sm * xs + 4096.f * sh;
}

// gather: Wq_g/Wk_g [256][512] bf16 (row-gathered, NO scale fold — modulation
// lives in G); WvT_g [512][256] bf16; wo_g [512][256] bf16; bias vectors.
__global__ void k_gather2(const int* __restrict__ idx,
                          const float* __restrict__ wq, const float* __restrict__ wk,
                          const float* __restrict__ wv, const float* __restrict__ wo,
                          const float* __restrict__ bq, const float* __restrict__ bk,
                          const float* __restrict__ bv,
                          bf16* __restrict__ Wqg, bf16* __restrict__ Wkg,
                          bf16* __restrict__ WvT, bf16* __restrict__ wog,
                          float* __restrict__ bqg, float* __restrict__ bkg,
                          float* __restrict__ bvg)
{
    const int b = blockIdx.z;
    const int* id = idx + b * 256;
    const int tid = blockIdx.x * 256 + threadIdx.x;     // < 131072
    {
        const int j = tid >> 9, c = tid & 511;
        const int ch = id[j];
        Wqg[(size_t)b * 131072 + tid] = f2b(wq[(size_t)ch * 512 + c]);
        Wkg[(size_t)b * 131072 + tid] = f2b(wk[(size_t)ch * 512 + c]);
    }
    {
        const int c = tid >> 8, j = tid & 255;
        const int ch = id[j];
        WvT[(size_t)b * 131072 + tid] = f2b(wv[(size_t)ch * 512 + c]);
        wog[(size_t)b * 131072 + tid] = f2b(wo[(size_t)(tid >> 8) * 512 + id[j]]);
    }
    if (tid < 256) {
        const int ch = id[tid];
        bqg[b * 256 + tid] = bq[ch];
        bkg[b * 256 + tid] = bk[ch];
        bvg[b * 256 + tid] = bv[ch];
    }
}

// qrow[i] = Wq_g[i] . rsh ; krow[i] = Wk_g[i] . rsh  (rank-1 S bias terms)
__global__ void k_vecs(const int* __restrict__ idx, const float* __restrict__ rsh,
                       const float* __restrict__ wq, const float* __restrict__ wk,
                       float* __restrict__ qrow, float* __restrict__ krow)
{
    const int gw = (blockIdx.x * 256 + threadIdx.x) >> 6;
    const int lane = threadIdx.x & 63;
    if (gw >= 8 * 512) return;
    const int b = gw >> 9, r = gw & 511;
    const int i = r & 255, sel = r >> 8;
    const int ch = idx[b * 256 + i];
    const float* W = sel ? wk : wq;
    float s = 0.f;
    for (int c = lane; c < 512; c += 64)
        s += W[(size_t)ch * 512 + c] * rsh[b * 512 + c];
    for (int off = 32; off; off >>= 1) s += __shfl_down(s, off);
    if (lane == 0) (sel ? krow : qrow)[b * 256 + i] = s;
}

// G[c][d] = smod_c smod_d Gx + smod_c shm_d xst_c + smod_d shm_c xst_d
//           + 4096 shm_c shm_d   (sum 2 split-K partials of Gx); bf16 out
__global__ void k_gmod(const float* __restrict__ part,
                       const float* __restrict__ smod, const float* __restrict__ shm,
                       const float* __restrict__ xst, bf16* __restrict__ G)
{
    const int b = blockIdx.x >> 9, c = blockIdx.x & 511;
    const float sc = smod[b * 512 + c], hc = shm[b * 512 + c], xc = xst[b * 512 + c];
#pragma unroll
    for (int h = 0; h < 2; ++h) {
        const int d = threadIdx.x + h * 256;
        const size_t o = (size_t)b * 262144 + (size_t)c * 512 + d;
        float g = part[o] + part[2097152 + o];
        const float sd = smod[b * 512 + d], hd = shm[b * 512 + d], xd = xst[b * 512 + d];
        G[o] = f2b(sc * sd * g + sc * hd * xc + sd * hc * xd + 4096.f * hc * hd);
    }
}

// softmax over S rows (+rank-1 bias terms), scale 1/16; attn bf16; ew = attn@bv_g
__global__ void k_soft2(const float* __restrict__ S0,
                        const float* __restrict__ qrow, const float* __restrict__ krow,
                        const float* __restrict__ bqg, const float* __restrict__ bkg,
                        const float* __restrict__ bvg,
                        bf16* __restrict__ attn, float* __restrict__ ew)
{
    const int row = blockIdx.x;          // b*256 + i
    const int b = row >> 8, i = row & 255;
    const int t = threadIdx.x;
    const int lane = t & 63, wvi = t >> 6;
    __shared__ float redm[4], reds[4], rede[4];
    const float bqi = bqg[b * 256 + i], qri = qrow[b * 256 + i];
    float v = S0[(size_t)b * 65536 + (size_t)i * 256 + t];
    v = (v + bqi * krow[b * 256 + t] + qri * bkg[b * 256 + t]
           + 4096.f * bqi * bkg[b * 256 + t]) * 0.0625f;
    float m = v;
    for (int off = 32; off; off >>= 1) m = fmaxf(m, __shfl_down(m, off));
    if (lane == 0) redm[wvi] = m;
    __syncthreads();
    m = fmaxf(fmaxf(redm[0], redm[1]), fmaxf(redm[2], redm[3]));
    const float e = __expf(v - m);
    float s = e;
    for (int off = 32; off; off >>= 1) s += __shfl_down(s, off);
    if (lane == 0) reds[wvi] = s;
    __syncthreads();
    s = reds[0] + reds[1] + reds[2] + reds[3];
    const float a = e / s;
    attn[(size_t)b * 65536 + (size_t)i * 256 + t] = f2b(a);
    float ev = a * bvg[b * 256 + t];
    for (int off = 32; off; off >>= 1) ev += __shfl_down(ev, off);
    if (lane == 0) rede[wvi] = ev;
    __syncthreads();
    if (t == 0) ew[b * 256 + i] = rede[0] + rede[1] + rede[2] + rede[3];
}

// M2[o][c] = M[o][c]*smod_c (bf16);  c1[o] = M[o].shm + wo_g[o].ew + bo[o]
__global__ void k_m2x(const float* __restrict__ Mmat, const float* __restrict__ smod,
                      const float* __restrict__ shm, const bf16* __restrict__ wog,
                      const float* __restrict__ ew, const float* __restrict__ bo,
                      bf16* __restrict__ M2, float* __restrict__ c1)
{
    const int b = blockIdx.x >> 9, o = blockIdx.x & 511;
    const int t = threadIdx.x;
    const int lane = t & 63, wvi = t >> 6;
    __shared__ float red[4];
    float p = 0.f;
#pragma unroll
    for (int h = 0; h < 2; ++h) {
        const int c = t + h * 256;
        const size_t off = (size_t)b * 262144 + (size_t)o * 512 + c;
        const float mv = Mmat[off];
        M2[off] = f2b(mv * smod[b * 512 + c]);
        p += mv * shm[b * 512 + c];
    }
    p += b2f(wog[(size_t)b * 131072 + (size_t)o * 256 + t]) * ew[b * 256 + t];
    for (int off = 32; off; off >>= 1) p += __shfl_down(p, off);
    if (lane == 0) red[wvi] = p;
    __syncthreads();
    if (t == 0) c1[b * 512 + o] = red[0] + red[1] + red[2] + red[3] + bo[o];
}

// ---------------------------------------------------------------------------

extern "C" void kernel_launch(void* const* d_in, const int* in_sizes, int n_in,
                              void* d_out, int out_size, void* d_ws, size_t ws_size,
                              hipStream_t stream)
{
    const float* x        = (const float*)d_in[0];
    const float* temb     = (const float*)d_in[1];
    const float* w_affine = (const float*)d_in[2];
    const float* b_affine = (const float*)d_in[3];
    const float* w_tp     = (const float*)d_in[4];
    const float* b_tp     = (const float*)d_in[5];
    const float* w_m1     = (const float*)d_in[6];
    const float* b_m1     = (const float*)d_in[7];
    const float* w_m2     = (const float*)d_in[8];
    const float* b_m2     = (const float*)d_in[9];
    const float* wq       = (const float*)d_in[10];
    const float* bq       = (const float*)d_in[11];
    const float* wk       = (const float*)d_in[12];
    const float* bk       = (const float*)d_in[13];
    const float* wv       = (const float*)d_in[14];
    const float* bv       = (const float*)d_in[15];
    const float* wo       = (const float*)d_in[16];
    const float* bo       = (const float*)d_in[17];
    float* out = (float*)d_out;

    char* ws = (char*)d_ws;
    size_t off = 0;
    auto alloc = [&](size_t bytes) -> char* {
        char* p = ws + off;
        off += (bytes + 255) & ~(size_t)255;
        return p;
    };

    float* ssb    = (float*)alloc(8192 * 4);
    float* tp     = (float*)alloc(4096 * 4);
    float* xsump  = (float*)alloc((size_t)8 * 4096 * 4);
    float* hidden = (float*)alloc(8192 * 4);
    float* prompt = (float*)alloc(4096 * 4);
    int*   idx    = (int*)alloc(2048 * 4);
    float* smod   = (float*)alloc(4096 * 4);
    float* shm    = (float*)alloc(4096 * 4);
    float* xst    = (float*)alloc(4096 * 4);
    float* rsh    = (float*)alloc(4096 * 4);
    float* qrow   = (float*)alloc(2048 * 4);
    float* krow   = (float*)alloc(2048 * 4);
    float* bqg    = (float*)alloc(2048 * 4);
    float* bkg    = (float*)alloc(2048 * 4);
    float* bvg    = (float*)alloc(2048 * 4);
    float* ew     = (float*)alloc(2048 * 4);
    float* c1     = (float*)alloc(4096 * 4);
    bf16*  xb     = (bf16*)alloc((size_t)8 * 512 * 4096 * 2);   // 33.6 MB
    bf16*  xT     = (bf16*)alloc((size_t)8 * 4096 * 512 * 2);   // 33.6 MB
    bf16*  G      = (bf16*)alloc((size_t)8 * 512 * 512 * 2);    // 4.2 MB
    bf16*  Wqg    = (bf16*)alloc((size_t)8 * 256 * 512 * 2);
    bf16*  Wkg    = (bf16*)alloc((size_t)8 * 256 * 512 * 2);
    bf16*  WvT    = (bf16*)alloc((size_t)8 * 512 * 256 * 2);
    bf16*  wog    = (bf16*)alloc((size_t)8 * 512 * 256 * 2);
    // union region (19.93 MB): part (2 Gram split-K partials, 16.78 MB) dies
    // at k_gmod BEFORE any of the later tensors is written.
    char*  uni  = alloc((size_t)20 * 1024 * 1024);
    float* part = (float*)uni;                                   // [2][8][512][512] f32
    bf16*  T    = (bf16*)uni;                                    // [8][256][512]  @0
    bf16*  attn = (bf16*)(uni + 2097152);                        // [8][256][256]
    bf16*  Ut   = (bf16*)(uni + 3145728);                        // [8][512][256]
    float* S0   = (float*)(uni + 5242880);                       // [8][256][256] f32
    float* Mmat = (float*)(uni + 7340032);                       // [8][512][512] f32
    bf16*  M2   = (bf16*)(uni + 15728640);                       // [8][512][512] bf16
    (void)ws_size; (void)n_in; (void)in_sizes; (void)out_size;

    // 1. x -> xb (natural bf16), xT (transposed bf16), channel sums
    k_prep2<<<dim3(8, 8, 8), 256, 0, stream>>>(x, xb, xT, xsump);

    // 2. Gram: Gx = xb @ xb^T, split-K=2 (k-chunks of 2048). grid 8*8*4*2=512
    gemm_bt2<float><<<512, 256, 0, stream>>>(
        xb, 2097152, 4096, xb, 2097152, 4096,
        nullptr, 0, 0,
        part, 262144, 2097152, 512, 512, 2048, 0, 8, 4);

    // 3. temb chain (silu fused into input reads)
    k_smallgemm<<<2048, 256, 0, stream>>>(temb, w_affine, b_affine, ssb, 8, 1024, 512, 0, 1);
    k_smallgemm<<<1024, 256, 0, stream>>>(temb, w_tp, b_tp, tp, 8, 512, 512, 0, 1);
    k_mod<<<16, 256, 0, stream>>>(ssb, xsump, smod, shm, xst, rsh);
    k_mlp1<<<2048, 256, 0, stream>>>(ssb, xsump, tp, w_m1, b_m1, hidden);
    k_smallgemm<<<1024, 256, 0, stream>>>(hidden, w_m2, b_m2, prompt, 8, 512, 1024, 0, 0);
    k_topk<<<8, 512, 0, stream>>>(prompt, idx);

    // 4. gathers + rank-1 vectors
    k_gather2<<<dim3(512, 1, 8), 256, 0, stream>>>(idx, wq, wk, wv, wo, bq, bk, bv,
                                                   Wqg, Wkg, WvT, wog, bqg, bkg, bvg);
    k_vecs<<<1024, 256, 0, stream>>>(idx, rsh, wq, wk, qrow, krow);

    // 5. G = modulated Gram (bf16); part dies here
    k_gmod<<<4096, 256, 0, stream>>>(part, smod, shm, xst, G);

    // 6. T = Wq_g @ G   [256][512] bf16   (G symmetric -> Bt = G)
    gemm_bt2<bf16><<<128, 256, 0, stream>>>(
        Wqg, 131072, 512, G, 262144, 512,
        nullptr, 0, 0,
        T, 131072, 0, 256, 512, 512, 0, 8, 2);

    // 7. S0 = T @ Wk_g^T  [256][256] f32
    gemm_bt2<float><<<64, 256, 0, stream>>>(
        T, 131072, 512, Wkg, 131072, 512,
        nullptr, 0, 0,
        S0, 65536, 0, 256, 256, 512, 0, 4, 2);

    // 8. softmax (+rank-1 bias terms) -> attn bf16, ew = attn@bv_g
    k_soft2<<<2048, 256, 0, stream>>>(S0, qrow, krow, bqg, bkg, bvg, attn, ew);

    // 9. U^T = (attn @ Wv_g)^T  [512][256] bf16 (transStore)
    gemm_bt2<bf16><<<128, 256, 0, stream>>>(
        attn, 65536, 256, WvT, 131072, 256,
        nullptr, 0, 0,
        Ut, 131072, 0, 256, 512, 256, 1, 8, 2);

    // 10. M = wo_g @ U  [512][512] f32
    gemm_bt2<float><<<256, 256, 0, stream>>>(
        wog, 131072, 256, Ut, 131072, 256,
        nullptr, 0, 0,
        Mmat, 262144, 0, 512, 512, 256, 0, 8, 4);

    // 11. M2 = M * smod (bf16); c1 = M.shm + wo_g.ew + bo
    k_m2x<<<4096, 256, 0, stream>>>(Mmat, smod, shm, wog, ew, bo, M2, c1);

    // 12. out = M2 @ x + c1  (Bt = xT). grid 8*64*4 = 2048
    gemm_bt2<float><<<2048, 256, 0, stream>>>(
        M2, 262144, 512, xT, 2097152, 512,
        c1, 512, 1,
        out, 2097152, 0, 512, 4096, 512, 0, 64, 4);
}